// Round 1
// baseline (143.645 us; speedup 1.0000x reference)
//
#include <hip/hip_runtime.h>
#include <math.h>

#define CB 16          // class_bit (fixed by problem shape)
#define ALPHA 0.1f

__global__ void init_inv_kernel(int* __restrict__ inv, int n_train) {
    int t = blockIdx.x * blockDim.x + threadIdx.x;
    if (t < n_train) inv[t] = -1;
}

__global__ void scatter_inv_kernel(const int* __restrict__ ind,
                                   int* __restrict__ inv, int n_bs) {
    int b = blockIdx.x * blockDim.x + threadIdx.x;
    if (b < n_bs) inv[ind[b]] = b;
}

__device__ inline float block_reduce_256(float v, float* red) {
    // wave64 reduce
    #pragma unroll
    for (int off = 32; off > 0; off >>= 1) v += __shfl_down(v, off, 64);
    int lane = threadIdx.x & 63;
    int wid  = threadIdx.x >> 6;
    if (lane == 0) red[wid] = v;
    __syncthreads();
    float s = 0.f;
    if (threadIdx.x == 0) {
        int nw = blockDim.x >> 6;
        for (int w = 0; w < nw; ++w) s += red[w];
    }
    return s;
}

// u_[b,c,d] = sum_k u[b,k] * w_D[c,k,d]; also quantization partials
__global__ __launch_bounds__(256) void compute_u_kernel(
        const float* __restrict__ u, const float* __restrict__ w_D,
        float* __restrict__ u_, float* __restrict__ quant_partials,
        int n_bs, int bit, int n_cls) {
    __shared__ float red[4];
    int idx = blockIdx.x * blockDim.x + threadIdx.x;
    int total = n_bs * n_cls * CB;
    float q = 0.f;
    if (idx < total) {
        int d = idx & (CB - 1);
        int c = (idx / CB) % n_cls;
        int b = idx / (CB * n_cls);
        const float* __restrict__ ur = u + (size_t)b * bit;
        const float* __restrict__ w  = w_D + (size_t)c * bit * CB + d;
        float s = 0.f;
        for (int k = 0; k < bit; ++k) s = fmaf(ur[k], w[k * CB], s);
        u_[idx] = s;
        float sgn = (s > 0.f) ? 1.f : ((s < 0.f) ? -1.f : 0.f);
        float dd = s - sgn;
        q = dd * dd;
    }
    float bs = block_reduce_256(q, red);
    if (threadIdx.x == 0) quant_partials[blockIdx.x] = bs;
}

// Per block: one class c, 256 t-values. u_[:,c,:] + y[:,c] staged in LDS.
// ip[b,t,c] = sum_d U_eff[t,c,d]*u_[b,c,d];
// elem = log1p(exp(-|ip|)) + max(ip,0) - y[b,c]*Y_eff[t,c]*ip
__global__ __launch_bounds__(256) void loss_main_kernel(
        const float* __restrict__ y, const float* __restrict__ U,
        const float* __restrict__ Yb, const float* __restrict__ u_,
        const int* __restrict__ inv, float* __restrict__ like_partials,
        int n_bs, int n_cls, int n_train) {
    __shared__ float u_lds[128 * CB];
    __shared__ float ys[128];
    __shared__ float red[4];
    const int c   = blockIdx.y;
    const int tid = threadIdx.x;
    const int t   = blockIdx.x * blockDim.x + tid;

    // stage u_[:, c, :] (n_bs x CB) as float4
    const int nf4 = n_bs * (CB / 4);
    for (int f = tid; f < nf4; f += blockDim.x) {
        int b  = f / (CB / 4);
        int d4 = f & (CB / 4 - 1);
        ((float4*)u_lds)[f] =
            *(const float4*)(u_ + (size_t)b * n_cls * CB + (size_t)c * CB + (size_t)d4 * 4);
    }
    if (tid < n_bs) ys[tid] = y[(size_t)tid * n_cls + c];
    __syncthreads();

    float acc = 0.f;
    if (t < n_train) {
        float Ureg[CB];
        float Yv;
        int iv = inv[t];
        if (iv >= 0) {
            // row replaced by this batch: U_eff[t] = u_[iv,c,:], Y_eff = y[iv,c]
            #pragma unroll
            for (int d = 0; d < CB; ++d) Ureg[d] = u_lds[iv * CB + d];
            Yv = ys[iv];
        } else {
            const float* __restrict__ Up = U + (size_t)t * n_cls * CB + (size_t)c * CB;
            #pragma unroll
            for (int d4 = 0; d4 < CB / 4; ++d4) {
                float4 v = *(const float4*)(Up + d4 * 4);
                Ureg[d4 * 4 + 0] = v.x; Ureg[d4 * 4 + 1] = v.y;
                Ureg[d4 * 4 + 2] = v.z; Ureg[d4 * 4 + 3] = v.w;
            }
            Yv = Yb[(size_t)t * n_cls + c];
        }
        for (int b = 0; b < n_bs; ++b) {
            const float4* __restrict__ ub = (const float4*)(u_lds + b * CB);
            float ip = 0.f;
            #pragma unroll
            for (int d4 = 0; d4 < CB / 4; ++d4) {
                float4 v = ub[d4];           // wave-uniform address -> LDS broadcast
                ip = fmaf(Ureg[d4 * 4 + 0], v.x, ip);
                ip = fmaf(Ureg[d4 * 4 + 1], v.y, ip);
                ip = fmaf(Ureg[d4 * 4 + 2], v.z, ip);
                ip = fmaf(Ureg[d4 * 4 + 3], v.w, ip);
            }
            float s = ys[b] * Yv;
            float e = __expf(-fabsf(ip));
            float l = __logf(1.f + e);
            acc += l + fmaxf(ip, 0.f) - s * ip;
        }
    }
    float bs = block_reduce_256(acc, red);
    if (tid == 0) like_partials[(size_t)blockIdx.y * gridDim.x + blockIdx.x] = bs;
}

__global__ __launch_bounds__(256) void finalize_kernel(
        const float* __restrict__ like_partials, int n_like,
        const float* __restrict__ quant_partials, int n_quant,
        float* __restrict__ out, float like_scale, float quant_scale) {
    __shared__ double rs[256];
    __shared__ double rq[256];
    double s = 0.0, q = 0.0;
    for (int i = threadIdx.x; i < n_like; i += 256) s += (double)like_partials[i];
    for (int i = threadIdx.x; i < n_quant; i += 256) q += (double)quant_partials[i];
    rs[threadIdx.x] = s; rq[threadIdx.x] = q;
    __syncthreads();
    for (int off = 128; off > 0; off >>= 1) {
        if (threadIdx.x < off) {
            rs[threadIdx.x] += rs[threadIdx.x + off];
            rq[threadIdx.x] += rq[threadIdx.x + off];
        }
        __syncthreads();
    }
    if (threadIdx.x == 0)
        out[0] = (float)(rs[0] * (double)like_scale + rq[0] * (double)quant_scale);
}

extern "C" void kernel_launch(void* const* d_in, const int* in_sizes, int n_in,
                              void* d_out, int out_size, void* d_ws, size_t ws_size,
                              hipStream_t stream) {
    const float* u   = (const float*)d_in[0];
    const float* y   = (const float*)d_in[1];
    const int*   ind = (const int*)d_in[2];   // jax default x64-disabled -> int32
    const float* U   = (const float*)d_in[3];
    const float* Yb  = (const float*)d_in[4];
    const float* w_D = (const float*)d_in[5];

    const int n_bs    = in_sizes[2];             // 128
    const int bit     = in_sizes[0] / n_bs;      // 48
    const int n_cls   = in_sizes[1] / n_bs;      // 100
    const int n_train = in_sizes[4] / n_cls;     // 10000

    char* ws = (char*)d_ws;
    float* u_ = (float*)ws;
    size_t off = (size_t)n_bs * n_cls * CB * sizeof(float);
    int* inv = (int*)(ws + off);
    off += (size_t)n_train * sizeof(int);
    const int totalU = n_bs * n_cls * CB;
    const int nub = (totalU + 255) / 256;
    float* quant_partials = (float*)(ws + off);
    off += (size_t)nub * sizeof(float);
    const int gx = (n_train + 255) / 256;
    const int gy = n_cls;
    float* like_partials = (float*)(ws + off);

    init_inv_kernel<<<(n_train + 255) / 256, 256, 0, stream>>>(inv, n_train);
    scatter_inv_kernel<<<(n_bs + 255) / 256, 256, 0, stream>>>(ind, inv, n_bs);
    compute_u_kernel<<<nub, 256, 0, stream>>>(u, w_D, u_, quant_partials,
                                              n_bs, bit, n_cls);
    loss_main_kernel<<<dim3(gx, gy), 256, 0, stream>>>(y, U, Yb, u_, inv,
                                                       like_partials,
                                                       n_bs, n_cls, n_train);
    const float like_scale  = 1.0f / ((float)n_bs * (float)n_train * (float)n_cls);
    const float quant_scale = ALPHA / (float)totalU;
    finalize_kernel<<<1, 256, 0, stream>>>(like_partials, gx * gy,
                                           quant_partials, nub,
                                           (float*)d_out, like_scale, quant_scale);
}

// Round 2
// 109.629 us; speedup vs baseline: 1.3103x; 1.3103x over previous
//
#include <hip/hip_runtime.h>
#include <math.h>

#define CB 16          // class_bit
#define ALPHA 0.1f

typedef __bf16 bf16x8 __attribute__((ext_vector_type(8)));
typedef float  f32x16 __attribute__((ext_vector_type(16)));

__device__ __forceinline__ unsigned int f2bf(float x) {
    unsigned int u = __float_as_uint(x);
    return (u + 0x7FFFu + ((u >> 16) & 1u)) >> 16;   // RNE f32->bf16 bits
}

__global__ void init_inv_kernel(int* __restrict__ inv, int n_train) {
    int t = blockIdx.x * blockDim.x + threadIdx.x;
    if (t < n_train) inv[t] = -1;
}

__global__ void scatter_inv_kernel(const int* __restrict__ ind,
                                   int* __restrict__ inv, int n_bs) {
    int b = blockIdx.x * blockDim.x + threadIdx.x;
    if (b < n_bs) inv[ind[b]] = b;
}

__device__ inline float block_reduce_256(float v, float* red) {
    #pragma unroll
    for (int off = 32; off > 0; off >>= 1) v += __shfl_down(v, off, 64);
    int lane = threadIdx.x & 63;
    int wid  = threadIdx.x >> 6;
    if (lane == 0) red[wid] = v;
    __syncthreads();
    float s = 0.f;
    if (threadIdx.x == 0) {
        int nw = blockDim.x >> 6;
        for (int w = 0; w < nw; ++w) s += red[w];
    }
    return s;
}

// u_[b,c,d] = sum_k u[b,k]*w_D[c,k,d]; writes f32 [b][c][d], bf16 [c][b][d],
// and quantization partials.
__global__ __launch_bounds__(256) void compute_u_kernel(
        const float* __restrict__ u, const float* __restrict__ w_D,
        float* __restrict__ u_f32, unsigned short* __restrict__ u_bf,
        float* __restrict__ quant_partials, int n_bs, int bit, int n_cls) {
    __shared__ float red[4];
    int idx = blockIdx.x * blockDim.x + threadIdx.x;
    int total = n_bs * n_cls * CB;
    float q = 0.f;
    if (idx < total) {
        int d = idx & (CB - 1);
        int c = (idx / CB) % n_cls;
        int b = idx / (CB * n_cls);
        const float* __restrict__ ur = u + (size_t)b * bit;
        const float* __restrict__ w  = w_D + (size_t)c * bit * CB + d;
        float s = 0.f;
        for (int k = 0; k < bit; ++k) s = fmaf(ur[k], w[k * CB], s);
        u_f32[idx] = s;
        u_bf[((size_t)c * n_bs + b) * CB + d] = (unsigned short)f2bf(s);
        float sgn = (s > 0.f) ? 1.f : ((s < 0.f) ? -1.f : 0.f);
        float dd = s - sgn;
        q = dd * dd;
    }
    float bs = block_reduce_256(q, red);
    if (threadIdx.x == 0) quant_partials[blockIdx.x] = bs;
}

// v[c,d] = sum_b y[b,c]*u_[b,c,d];  w[c,d] = sum_b u_[b,c,d]
__global__ __launch_bounds__(256) void compute_vw_kernel(
        const float* __restrict__ y, const float* __restrict__ u_f32,
        float* __restrict__ vvec, float* __restrict__ wvec,
        int n_bs, int n_cls) {
    int idx = blockIdx.x * blockDim.x + threadIdx.x;
    if (idx >= n_cls * CB) return;
    int c = idx / CB, d = idx & (CB - 1);
    float v = 0.f, w = 0.f;
    for (int b = 0; b < n_bs; ++b) {
        float x = u_f32[((size_t)b * n_cls + c) * CB + d];
        w += x;
        v = fmaf(y[(size_t)b * n_cls + c], x, v);
    }
    vvec[idx] = v;
    wvec[idx] = w;
}

// One block = one 32-row t-tile x 4 consecutive classes (one class per wave).
// Per wave: A-frag = U_eff rows (bf16), B-frags = u_bf (4 b-tiles of 32),
// 4 MFMAs 32x32x16, softplus-only epilogue on 64 ip values per lane.
// Linear terms (sum ip, sum s*ip) collapsed into per-row side dots with v,w.
// Assumes n_cls % 4 == 0 (100) and n_bs == 128.
__global__ __launch_bounds__(256) void loss_main_mfma(
        const float* __restrict__ y, const float* __restrict__ U,
        const float* __restrict__ Yb, const float* __restrict__ u_f32,
        const unsigned short* __restrict__ u_bf,
        const float* __restrict__ vvec, const float* __restrict__ wvec,
        const int* __restrict__ inv, float* __restrict__ partials,
        int n_bs, int n_cls, int n_train) {
    __shared__ float red[4 * 4];
    const int lane = threadIdx.x & 63;
    const int wid  = threadIdx.x >> 6;
    const int c    = blockIdx.x * 4 + wid;     // class for this wave
    const int t0   = blockIdx.y * 32;
    const int r    = lane & 31;                // A: row-in-tile; B: col-in-tile
    const int h    = lane >> 5;                // k-half (k = h*8 + j)
    const int row  = t0 + r;

    const bool valid = (row < n_train);
    const int rc = valid ? row : (n_train - 1);
    const int iv = inv[rc];

    // A row (f32), with batch-replacement (U_eff) via address select
    const float* __restrict__ arow = (iv >= 0)
        ? (u_f32 + ((size_t)iv * n_cls + c) * CB)
        : (U     + ((size_t)rc * n_cls + c) * CB);
    float4 a0 = *(const float4*)(arow + h * 8);
    float4 a1 = *(const float4*)(arow + h * 8 + 4);
    float Yv = (iv >= 0) ? y[(size_t)iv * n_cls + c]
                         : Yb[(size_t)rc * n_cls + c];
    if (!valid) {
        a0 = make_float4(0.f, 0.f, 0.f, 0.f);
        a1 = make_float4(0.f, 0.f, 0.f, 0.f);
        Yv = 0.f;
    }

    // side dots: sum_b s*ip and sum_b ip, collapsed to U_row . v / U_row . w
    const float* __restrict__ vp = vvec + (size_t)c * CB + h * 8;
    const float* __restrict__ wp = wvec + (size_t)c * CB + h * 8;
    float sv = a0.x*vp[0] + a0.y*vp[1] + a0.z*vp[2] + a0.w*vp[3]
             + a1.x*vp[4] + a1.y*vp[5] + a1.z*vp[6] + a1.w*vp[7];
    float sw = a0.x*wp[0] + a0.y*wp[1] + a0.z*wp[2] + a0.w*wp[3]
             + a1.x*wp[4] + a1.y*wp[5] + a1.z*wp[6] + a1.w*wp[7];
    float sideS = Yv * sv;   // contributes to sum s*ip
    float sideW = sw;        // contributes to sum ip

    union { unsigned int u32[4]; bf16x8 v; } A;
    A.u32[0] = f2bf(a0.x) | (f2bf(a0.y) << 16);
    A.u32[1] = f2bf(a0.z) | (f2bf(a0.w) << 16);
    A.u32[2] = f2bf(a1.x) | (f2bf(a1.y) << 16);
    A.u32[3] = f2bf(a1.z) | (f2bf(a1.w) << 16);

    // B fragments: u_bf [c][b][d], lane = col b0+r, k-half h
    const unsigned short* __restrict__ ub = u_bf + (size_t)c * n_bs * CB;
    bf16x8 B[4];
    #pragma unroll
    for (int bt = 0; bt < 4; ++bt)
        B[bt] = *(const bf16x8*)(ub + (size_t)(bt * 32 + r) * CB + h * 8);

    const float c_nlog2e = -1.4426950408889634f;
    float accL = 0.f;   // sum log2(1 + 2^(-|ip|*log2e))   (pad rows add exactly 1)
    float accA = 0.f;   // sum |ip|
    f32x16 zc = {};
    #pragma unroll
    for (int bt = 0; bt < 4; ++bt) {
        f32x16 D = __builtin_amdgcn_mfma_f32_32x32x16_bf16(A.v, B[bt], zc, 0, 0, 0);
        #pragma unroll
        for (int j = 0; j < 16; ++j) {
            float ip  = D[j];
            float ipa = fabsf(ip);
            float e   = __builtin_amdgcn_exp2f(ipa * c_nlog2e);
            float lg  = __builtin_amdgcn_logf(1.0f + e);   // v_log_f32 = log2
            accL += lg;
            accA += ipa;
        }
    }

    #pragma unroll
    for (int off = 32; off > 0; off >>= 1) {
        accL  += __shfl_down(accL,  off, 64);
        accA  += __shfl_down(accA,  off, 64);
        sideS += __shfl_down(sideS, off, 64);
        sideW += __shfl_down(sideW, off, 64);
    }
    if (lane == 0) {
        red[wid * 4 + 0] = accL;
        red[wid * 4 + 1] = accA;
        red[wid * 4 + 2] = sideS;
        red[wid * 4 + 3] = sideW;
    }
    __syncthreads();
    if (threadIdx.x < 4) {
        float s = red[0 * 4 + threadIdx.x] + red[1 * 4 + threadIdx.x]
                + red[2 * 4 + threadIdx.x] + red[3 * 4 + threadIdx.x];
        size_t bid = (size_t)blockIdx.y * gridDim.x + blockIdx.x;
        partials[bid * 4 + threadIdx.x] = s;
    }
}

__global__ __launch_bounds__(256) void finalize_kernel(
        const float* __restrict__ partials, int nblk,
        const float* __restrict__ quant_partials, int n_quant,
        float* __restrict__ out, double n_pad,
        double like_scale, double quant_scale) {
    double sL = 0, sA = 0, sS = 0, sW = 0, sQ = 0;
    for (int i = threadIdx.x; i < nblk; i += 256) {
        sL += (double)partials[i * 4 + 0];
        sA += (double)partials[i * 4 + 1];
        sS += (double)partials[i * 4 + 2];
        sW += (double)partials[i * 4 + 3];
    }
    for (int i = threadIdx.x; i < n_quant; i += 256) sQ += (double)quant_partials[i];
    #pragma unroll
    for (int off = 32; off > 0; off >>= 1) {
        sL += __shfl_down(sL, off, 64);
        sA += __shfl_down(sA, off, 64);
        sS += __shfl_down(sS, off, 64);
        sW += __shfl_down(sW, off, 64);
        sQ += __shfl_down(sQ, off, 64);
    }
    __shared__ double red[4][5];
    int lane = threadIdx.x & 63, wid = threadIdx.x >> 6;
    if (lane == 0) {
        red[wid][0] = sL; red[wid][1] = sA; red[wid][2] = sS;
        red[wid][3] = sW; red[wid][4] = sQ;
    }
    __syncthreads();
    if (threadIdx.x == 0) {
        double L = 0, Aa = 0, S = 0, W = 0, Q = 0;
        for (int w = 0; w < 4; ++w) {
            L += red[w][0]; Aa += red[w][1]; S += red[w][2];
            W += red[w][3]; Q  += red[w][4];
        }
        const double ln2 = 0.6931471805599453;
        // sum softplus = ln2*(L - n_pad) + 0.5*|ip|-sum + 0.5*ip-sum; minus s*ip
        double like = ln2 * (L - n_pad) + 0.5 * Aa + 0.5 * W - S;
        out[0] = (float)(like * like_scale + Q * quant_scale);
    }
}

extern "C" void kernel_launch(void* const* d_in, const int* in_sizes, int n_in,
                              void* d_out, int out_size, void* d_ws, size_t ws_size,
                              hipStream_t stream) {
    const float* u   = (const float*)d_in[0];
    const float* y   = (const float*)d_in[1];
    const int*   ind = (const int*)d_in[2];
    const float* U   = (const float*)d_in[3];
    const float* Yb  = (const float*)d_in[4];
    const float* w_D = (const float*)d_in[5];

    const int n_bs    = in_sizes[2];             // 128
    const int bit     = in_sizes[0] / n_bs;      // 48
    const int n_cls   = in_sizes[1] / n_bs;      // 100
    const int n_train = in_sizes[4] / n_cls;     // 10000

    const int totalU = n_bs * n_cls * CB;
    const int nub    = (totalU + 255) / 256;
    const int ntile  = (n_train + 31) / 32;      // 313
    const int gx     = (n_cls + 3) / 4;          // 25 (n_cls % 4 == 0)
    const int nblk   = ntile * gx;

    char* ws = (char*)d_ws;
    size_t off = 0;
    float* u_f32 = (float*)(ws + off);          off += (size_t)totalU * 4;
    unsigned short* u_bf = (unsigned short*)(ws + off); off += (size_t)totalU * 2;
    off = (off + 15) & ~(size_t)15;
    int* inv = (int*)(ws + off);                off += (size_t)n_train * 4;
    off = (off + 15) & ~(size_t)15;
    float* vvec = (float*)(ws + off);           off += (size_t)n_cls * CB * 4;
    float* wvec = (float*)(ws + off);           off += (size_t)n_cls * CB * 4;
    float* quant_partials = (float*)(ws + off); off += (size_t)nub * 4;
    off = (off + 15) & ~(size_t)15;
    float* partials = (float*)(ws + off);       off += (size_t)nblk * 4 * 4;

    init_inv_kernel<<<(n_train + 255) / 256, 256, 0, stream>>>(inv, n_train);
    scatter_inv_kernel<<<(n_bs + 255) / 256, 256, 0, stream>>>(ind, inv, n_bs);
    compute_u_kernel<<<nub, 256, 0, stream>>>(u, w_D, u_f32, u_bf,
                                              quant_partials, n_bs, bit, n_cls);
    compute_vw_kernel<<<(n_cls * CB + 255) / 256, 256, 0, stream>>>(
        y, u_f32, vvec, wvec, n_bs, n_cls);
    loss_main_mfma<<<dim3(gx, ntile), 256, 0, stream>>>(
        y, U, Yb, u_f32, u_bf, vvec, wvec, inv, partials, n_bs, n_cls, n_train);

    const double n_pad = (double)((long long)(ntile * 32 - n_train) *
                                  (long long)n_bs * (long long)n_cls);
    const double like_scale  = 1.0 / ((double)n_bs * n_train * n_cls);
    const double quant_scale = (double)ALPHA / (double)totalU;
    finalize_kernel<<<1, 256, 0, stream>>>(partials, nblk, quant_partials, nub,
                                           (float*)d_out, n_pad,
                                           like_scale, quant_scale);
}

// Round 3
// 59.793 us; speedup vs baseline: 2.4024x; 1.8335x over previous
//
#include <hip/hip_runtime.h>
#include <math.h>

#define CB 16          // class_bit
#define ALPHA 0.1f
#define LOG2E 1.4426950408889634f

typedef __bf16 bf16x8 __attribute__((ext_vector_type(8)));
typedef float  f32x16 __attribute__((ext_vector_type(16)));

__device__ __forceinline__ unsigned int f2bf(float x) {
    unsigned int u = __float_as_uint(x);
    return (u + 0x7FFFu + ((u >> 16) & 1u)) >> 16;   // RNE f32->bf16 bits
}

__device__ inline float block_reduce_256(float v, float* red) {
    #pragma unroll
    for (int off = 32; off > 0; off >>= 1) v += __shfl_down(v, off, 64);
    int lane = threadIdx.x & 63;
    int wid  = threadIdx.x >> 6;
    if (lane == 0) red[wid] = v;
    __syncthreads();
    float s = 0.f;
    if (threadIdx.x == 0) {
        int nw = blockDim.x >> 6;
        for (int w = 0; w < nw; ++w) s += red[w];
    }
    return s;
}

// u_[b,c,d] = sum_k u[b,k]*w_D[c,k,d]; writes f32 [b][c][d],
// bf16 [c][b][d] PRE-SCALED by log2(e), quantization partials, and inits inv.
__global__ __launch_bounds__(256) void compute_u_kernel(
        const float* __restrict__ u, const float* __restrict__ w_D,
        float* __restrict__ u_f32, unsigned short* __restrict__ u_bf,
        float* __restrict__ quant_partials, int* __restrict__ inv,
        int n_bs, int bit, int n_cls, int n_train) {
    __shared__ float red[4];
    int idx = blockIdx.x * blockDim.x + threadIdx.x;
    if (idx < n_train) inv[idx] = -1;          // piggybacked init (grid >> n_train)
    int total = n_bs * n_cls * CB;
    float q = 0.f;
    if (idx < total) {
        int d = idx & (CB - 1);
        int c = (idx / CB) % n_cls;
        int b = idx / (CB * n_cls);
        const float* __restrict__ ur = u + (size_t)b * bit;
        const float* __restrict__ w  = w_D + (size_t)c * bit * CB + d;
        float s = 0.f;
        for (int k = 0; k < bit; ++k) s = fmaf(ur[k], w[k * CB], s);
        u_f32[idx] = s;
        u_bf[((size_t)c * n_bs + b) * CB + d] = (unsigned short)f2bf(s * LOG2E);
        float sgn = (s > 0.f) ? 1.f : ((s < 0.f) ? -1.f : 0.f);
        float dd = s - sgn;
        q = dd * dd;
    }
    float bs = block_reduce_256(q, red);
    if (threadIdx.x == 0) quant_partials[blockIdx.x] = bs;
}

// One block per class. Also performs the inv scatter (block 0).
// v[c,d] = sum_b y[b,c]*u_[b,c,d];  w[c,d] = sum_b u_[b,c,d]
__global__ __launch_bounds__(256) void compute_vw_kernel(
        const float* __restrict__ y, const float* __restrict__ u_f32,
        const int* __restrict__ ind, int* __restrict__ inv,
        float* __restrict__ vvec, float* __restrict__ wvec,
        int n_bs, int n_cls) {
    if (blockIdx.x == 0 && threadIdx.x < n_bs)
        inv[ind[threadIdx.x]] = threadIdx.x;   // init done in prior kernel
    __shared__ float vs[16][17];
    __shared__ float wsh[16][17];
    const int c  = blockIdx.x;
    const int d  = threadIdx.x & (CB - 1);
    const int sl = threadIdx.x >> 4;           // 16 slices x 8 b's
    float v = 0.f, w = 0.f;
    const int bpp = n_bs >> 4;                 // 8
    for (int b = sl * bpp; b < (sl + 1) * bpp; ++b) {
        float x = u_f32[((size_t)b * n_cls + c) * CB + d];
        w += x;
        v = fmaf(y[(size_t)b * n_cls + c], x, v);
    }
    vs[sl][d] = v; wsh[sl][d] = w;
    __syncthreads();
    #pragma unroll
    for (int s = 8; s > 0; s >>= 1) {
        if (sl < s) {
            vs[sl][d]  += vs[sl + s][d];
            wsh[sl][d] += wsh[sl + s][d];
        }
        __syncthreads();
    }
    if (sl == 0) {
        vvec[(size_t)c * CB + d] = vs[0][d];
        wvec[(size_t)c * CB + d] = wsh[0][d];
    }
}

// One block = 32-row t-tile x 4 classes (one class per wave).
// ip' = ip*log2e via pre-scaled B. Epilogue: product-of-16 log amortization.
__global__ __launch_bounds__(256) void loss_main_mfma(
        const float* __restrict__ y, const float* __restrict__ U,
        const float* __restrict__ Yb, const float* __restrict__ u_f32,
        const unsigned short* __restrict__ u_bf,
        const float* __restrict__ vvec, const float* __restrict__ wvec,
        const int* __restrict__ inv, float* __restrict__ partials, int nblk,
        int n_bs, int n_cls, int n_train) {
    __shared__ float red[4 * 4];
    const int lane = threadIdx.x & 63;
    const int wid  = threadIdx.x >> 6;
    const int c    = blockIdx.x * 4 + wid;
    const int t0   = blockIdx.y * 32;
    const int r    = lane & 31;
    const int h    = lane >> 5;
    const int row  = t0 + r;

    const bool valid = (row < n_train);
    const int rc = valid ? row : (n_train - 1);
    const int iv = inv[rc];

    const float* __restrict__ arow = (iv >= 0)
        ? (u_f32 + ((size_t)iv * n_cls + c) * CB)
        : (U     + ((size_t)rc * n_cls + c) * CB);
    float4 a0 = *(const float4*)(arow + h * 8);
    float4 a1 = *(const float4*)(arow + h * 8 + 4);
    const float* __restrict__ yrow = (iv >= 0)
        ? (y  + (size_t)iv * n_cls + c)
        : (Yb + (size_t)rc * n_cls + c);
    float Yv = *yrow;
    if (!valid) {
        a0 = make_float4(0.f, 0.f, 0.f, 0.f);
        a1 = make_float4(0.f, 0.f, 0.f, 0.f);
        Yv = 0.f;
    }

    // side dots: collapse sum_b s*ip -> Yv*(U_row . v), sum_b ip -> U_row . w
    const float* __restrict__ vp = vvec + (size_t)c * CB + h * 8;
    const float* __restrict__ wp = wvec + (size_t)c * CB + h * 8;
    float sv = a0.x*vp[0] + a0.y*vp[1] + a0.z*vp[2] + a0.w*vp[3]
             + a1.x*vp[4] + a1.y*vp[5] + a1.z*vp[6] + a1.w*vp[7];
    float sw = a0.x*wp[0] + a0.y*wp[1] + a0.z*wp[2] + a0.w*wp[3]
             + a1.x*wp[4] + a1.y*wp[5] + a1.z*wp[6] + a1.w*wp[7];
    float sideS = Yv * sv;
    float sideW = sw;

    union { unsigned int u32[4]; bf16x8 v; } A;
    A.u32[0] = f2bf(a0.x) | (f2bf(a0.y) << 16);
    A.u32[1] = f2bf(a0.z) | (f2bf(a0.w) << 16);
    A.u32[2] = f2bf(a1.x) | (f2bf(a1.y) << 16);
    A.u32[3] = f2bf(a1.z) | (f2bf(a1.w) << 16);

    const unsigned short* __restrict__ ub = u_bf + (size_t)c * n_bs * CB;
    bf16x8 B[4];
    #pragma unroll
    for (int bt = 0; bt < 4; ++bt)
        B[bt] = *(const bf16x8*)(ub + (size_t)(bt * 32 + r) * CB + h * 8);

    float accL = 0.f;   // sum log2(1 + 2^(-|ip'|))  (pad rows add exactly 1)
    float accA = 0.f;   // sum |ip'|
    f32x16 zc = {};
    #pragma unroll
    for (int bt = 0; bt < 4; ++bt) {
        f32x16 D = __builtin_amdgcn_mfma_f32_32x32x16_bf16(A.v, B[bt], zc, 0, 0, 0);
        float a[16];
        #pragma unroll
        for (int j = 0; j < 16; ++j) {
            float ipa = fabsf(D[j]);
            a[j] = 1.0f + __builtin_amdgcn_exp2f(-ipa);  // neg-abs folds to src mod
            accA += ipa;
        }
        // product tree of 16: a in (1,2] -> prod in (1,65536], exact-safe
        #pragma unroll
        for (int s = 1; s < 16; s <<= 1)
            #pragma unroll
            for (int j = 0; j < 16; j += 2 * s) a[j] *= a[j + s];
        accL += __builtin_amdgcn_logf(a[0]);             // v_log_f32 = log2
    }

    #pragma unroll
    for (int off = 32; off > 0; off >>= 1) {
        accL  += __shfl_down(accL,  off, 64);
        accA  += __shfl_down(accA,  off, 64);
        sideS += __shfl_down(sideS, off, 64);
        sideW += __shfl_down(sideW, off, 64);
    }
    if (lane == 0) {
        red[wid * 4 + 0] = accL;
        red[wid * 4 + 1] = accA;
        red[wid * 4 + 2] = sideS;
        red[wid * 4 + 3] = sideW;
    }
    __syncthreads();
    if (threadIdx.x < 4) {
        float s = red[0 * 4 + threadIdx.x] + red[1 * 4 + threadIdx.x]
                + red[2 * 4 + threadIdx.x] + red[3 * 4 + threadIdx.x];
        int bid = blockIdx.y * gridDim.x + blockIdx.x;
        partials[(size_t)threadIdx.x * nblk + bid] = s;   // planar layout
    }
}

__global__ __launch_bounds__(256) void finalize_kernel(
        const float* __restrict__ partials, int nblk,
        const float* __restrict__ quant_partials, int n_quant,
        float* __restrict__ out, double n_pad,
        double like_scale, double quant_scale) {
    double sL = 0, sA = 0, sS = 0, sW = 0, sQ = 0;
    for (int i = threadIdx.x; i < nblk; i += 256) {
        sL += (double)partials[0 * nblk + i];
        sA += (double)partials[1 * nblk + i];
        sS += (double)partials[2 * nblk + i];
        sW += (double)partials[3 * nblk + i];
    }
    for (int i = threadIdx.x; i < n_quant; i += 256) sQ += (double)quant_partials[i];
    #pragma unroll
    for (int off = 32; off > 0; off >>= 1) {
        sL += __shfl_down(sL, off, 64);
        sA += __shfl_down(sA, off, 64);
        sS += __shfl_down(sS, off, 64);
        sW += __shfl_down(sW, off, 64);
        sQ += __shfl_down(sQ, off, 64);
    }
    __shared__ double red[4][5];
    int lane = threadIdx.x & 63, wid = threadIdx.x >> 6;
    if (lane == 0) {
        red[wid][0] = sL; red[wid][1] = sA; red[wid][2] = sS;
        red[wid][3] = sW; red[wid][4] = sQ;
    }
    __syncthreads();
    if (threadIdx.x == 0) {
        double L = 0, Aa = 0, S = 0, W = 0, Q = 0;
        for (int w = 0; w < 4; ++w) {
            L += red[w][0]; Aa += red[w][1]; S += red[w][2];
            W += red[w][3]; Q  += red[w][4];
        }
        const double ln2 = 0.6931471805599453;
        // Aa is sum|ip'| = log2e * sum|ip|  ->  0.5*sum|ip| = 0.5*ln2*Aa
        double like = ln2 * (L - n_pad + 0.5 * Aa) + 0.5 * W - S;
        out[0] = (float)(like * like_scale + Q * quant_scale);
    }
}

extern "C" void kernel_launch(void* const* d_in, const int* in_sizes, int n_in,
                              void* d_out, int out_size, void* d_ws, size_t ws_size,
                              hipStream_t stream) {
    const float* u   = (const float*)d_in[0];
    const float* y   = (const float*)d_in[1];
    const int*   ind = (const int*)d_in[2];
    const float* U   = (const float*)d_in[3];
    const float* Yb  = (const float*)d_in[4];
    const float* w_D = (const float*)d_in[5];

    const int n_bs    = in_sizes[2];             // 128
    const int bit     = in_sizes[0] / n_bs;      // 48
    const int n_cls   = in_sizes[1] / n_bs;      // 100
    const int n_train = in_sizes[4] / n_cls;     // 10000

    const int totalU = n_bs * n_cls * CB;
    const int nub    = (totalU + 255) / 256;     // 800 blocks (>= n_train/256)
    const int ntile  = (n_train + 31) / 32;      // 313
    const int gx     = (n_cls + 3) / 4;          // 25
    const int nblk   = ntile * gx;

    char* ws = (char*)d_ws;
    size_t off = 0;
    float* u_f32 = (float*)(ws + off);          off += (size_t)totalU * 4;
    unsigned short* u_bf = (unsigned short*)(ws + off); off += (size_t)totalU * 2;
    off = (off + 15) & ~(size_t)15;
    int* inv = (int*)(ws + off);                off += (size_t)n_train * 4;
    off = (off + 15) & ~(size_t)15;
    float* vvec = (float*)(ws + off);           off += (size_t)n_cls * CB * 4;
    float* wvec = (float*)(ws + off);           off += (size_t)n_cls * CB * 4;
    float* quant_partials = (float*)(ws + off); off += (size_t)nub * 4;
    off = (off + 15) & ~(size_t)15;
    float* partials = (float*)(ws + off);       off += (size_t)nblk * 4 * 4;

    compute_u_kernel<<<nub, 256, 0, stream>>>(u, w_D, u_f32, u_bf,
                                              quant_partials, inv,
                                              n_bs, bit, n_cls, n_train);
    compute_vw_kernel<<<n_cls, 256, 0, stream>>>(y, u_f32, ind, inv,
                                                 vvec, wvec, n_bs, n_cls);
    loss_main_mfma<<<dim3(gx, ntile), 256, 0, stream>>>(
        y, U, Yb, u_f32, u_bf, vvec, wvec, inv, partials, nblk,
        n_bs, n_cls, n_train);

    const double n_pad = (double)((long long)(ntile * 32 - n_train) *
                                  (long long)n_bs * (long long)n_cls);
    const double like_scale  = 1.0 / ((double)n_bs * n_train * n_cls);
    const double quant_scale = (double)ALPHA / (double)totalU;
    finalize_kernel<<<1, 256, 0, stream>>>(partials, nblk, quant_partials, nub,
                                           (float*)d_out, n_pad,
                                           like_scale, quant_scale);
}